// Round 1
// baseline (295.564 us; speedup 1.0000x reference)
//
#include <hip/hip_runtime.h>
#include <math.h>

#define D_FEAT 64
#define EPS 1e-7f

__device__ __forceinline__ float wave_reduce_sum(float v) {
    // 64-lane butterfly reduce
    #pragma unroll
    for (int off = 32; off > 0; off >>= 1)
        v += __shfl_xor(v, off, 64);
    return v;
}

// Kernel 1: per-node L2 norm.  One wave per node, lane = feature.
__global__ void agnn_norms(const float* __restrict__ x,
                           float* __restrict__ norms, int n_nodes) {
    int node = (blockIdx.x * blockDim.x + threadIdx.x) >> 6;
    if (node >= n_nodes) return;
    int lane = threadIdx.x & 63;
    float v = x[node * D_FEAT + lane];
    float ss = wave_reduce_sum(v * v);
    if (lane == 0) norms[node] = sqrtf(ss);
}

// Kernel 2: CSR row offsets via binary search (edge_row is sorted).
__global__ void agnn_rowptr(const int* __restrict__ edge_row,
                            int* __restrict__ row_ptr,
                            int n_nodes, int n_edges) {
    int i = blockIdx.x * blockDim.x + threadIdx.x;
    if (i > n_nodes) return;
    int lo = 0, hi = n_edges;
    while (lo < hi) {
        int mid = (lo + hi) >> 1;
        if (edge_row[mid] < i) lo = mid + 1; else hi = mid;
    }
    row_ptr[i] = lo;
}

// Kernel 3: fused sim + online softmax + SPMM.  One wave per node.
__global__ __launch_bounds__(256)
void agnn_fused(const float* __restrict__ x,
                const float* __restrict__ beta_p,
                const int* __restrict__ edge_col,
                const int* __restrict__ row_ptr,
                const float* __restrict__ norms,
                float* __restrict__ out, int n_nodes) {
    int node = (blockIdx.x * blockDim.x + threadIdx.x) >> 6;
    if (node >= n_nodes) return;
    int lane = threadIdx.x & 63;

    float xi   = x[node * D_FEAT + lane];
    float ni   = norms[node];
    float beta = beta_p[0];

    int e0 = row_ptr[node];
    int e1 = row_ptr[node + 1];

    float m = -INFINITY;   // running max
    float s = 0.0f;        // running sum of exp
    float acc = 0.0f;      // running weighted feature sum (per-lane)

    for (int e = e0; e < e1; ++e) {
        int c = edge_col[e];
        float xc = x[c * D_FEAT + lane];
        float inner = wave_reduce_sum(xi * xc);
        float nc = norms[c];
        float sim = beta * inner / (ni * nc + EPS);

        // online softmax update
        float mnew  = fmaxf(m, sim);
        float scale = __expf(m - mnew);    // exp(-inf)=0 on first edge
        float w     = __expf(sim - mnew);
        s   = s * scale + w;
        acc = acc * scale + w * xc;
        m   = mnew;
    }

    float o = (e1 > e0) ? (acc / s) : 0.0f;
    out[node * D_FEAT + lane] = o;
}

extern "C" void kernel_launch(void* const* d_in, const int* in_sizes, int n_in,
                              void* d_out, int out_size, void* d_ws, size_t ws_size,
                              hipStream_t stream) {
    const float* x        = (const float*)d_in[0];
    const float* beta     = (const float*)d_in[1];
    const int*   edge_row = (const int*)d_in[2];
    const int*   edge_col = (const int*)d_in[3];
    float* out = (float*)d_out;

    int n_nodes = in_sizes[0] / D_FEAT;
    int n_edges = in_sizes[2];

    // workspace layout: norms [n_nodes] floats, then row_ptr [n_nodes+1] ints
    float* norms  = (float*)d_ws;
    size_t norms_bytes = ((size_t)n_nodes * sizeof(float) + 255) & ~(size_t)255;
    int* row_ptr = (int*)((char*)d_ws + norms_bytes);

    // K1: norms — one wave per node, 4 waves per block
    {
        int waves_per_block = 256 / 64;
        int blocks = (n_nodes + waves_per_block - 1) / waves_per_block;
        agnn_norms<<<blocks, 256, 0, stream>>>(x, norms, n_nodes);
    }
    // K2: row_ptr
    {
        int blocks = (n_nodes + 1 + 255) / 256;
        agnn_rowptr<<<blocks, 256, 0, stream>>>(edge_row, row_ptr, n_nodes, n_edges);
    }
    // K3: fused
    {
        int waves_per_block = 256 / 64;
        int blocks = (n_nodes + waves_per_block - 1) / waves_per_block;
        agnn_fused<<<blocks, 256, 0, stream>>>(x, beta, edge_col, row_ptr, norms,
                                               out, n_nodes);
    }
}

// Round 2
// 163.338 us; speedup vs baseline: 1.8095x; 1.8095x over previous
//
#include <hip/hip_runtime.h>
#include <math.h>

#define D_FEAT 64

// Kernel 1: reciprocal L2 norms. 16 lanes per node, float4 per lane.
__global__ __launch_bounds__(256)
void agnn_rnorm(const float* __restrict__ x, float* __restrict__ rn, int n_nodes) {
    int t = blockIdx.x * blockDim.x + threadIdx.x;
    int node = t >> 4;
    if (node >= n_nodes) return;
    int l4 = t & 15;
    float4 v = ((const float4*)x)[node * 16 + l4];
    float ss = v.x * v.x + v.y * v.y + v.z * v.z + v.w * v.w;
    #pragma unroll
    for (int off = 1; off < 16; off <<= 1)
        ss += __shfl_xor(ss, off, 64);
    if (l4 == 0) rn[node] = ss > 0.f ? rsqrtf(ss) : 0.f;
}

// Kernel 2: CSR row offsets via binary search (edge_row is sorted).
__global__ void agnn_rowptr(const int* __restrict__ edge_row,
                            int* __restrict__ row_ptr,
                            int n_nodes, int n_edges) {
    int i = blockIdx.x * blockDim.x + threadIdx.x;
    if (i > n_nodes) return;
    int lo = 0, hi = n_edges;
    while (lo < hi) {
        int mid = (lo + hi) >> 1;
        if (edge_row[mid] < i) lo = mid + 1; else hi = mid;
    }
    row_ptr[i] = lo;
}

// Kernel 3: fused sim + softmax + SPMM.
// One wave per node; 4 groups of 16 lanes; group g handles edge (base+g),
// lane l4 within a group holds features [4*l4, 4*l4+4) as float4.
// Softmax uses the constant shift |beta| (valid since |cos|<=1) => no
// per-edge max/rescale dependency chain.
__global__ __launch_bounds__(256)
void agnn_fused(const float* __restrict__ x,
                const float* __restrict__ beta_p,
                const int* __restrict__ edge_col,
                const int* __restrict__ row_ptr,
                const float* __restrict__ rn,
                float* __restrict__ out, int n_nodes) {
    int node = (blockIdx.x * blockDim.x + threadIdx.x) >> 6;
    if (node >= n_nodes) return;
    int lane = threadIdx.x & 63;
    int g  = lane >> 4;    // edge subgroup 0..3
    int l4 = lane & 15;    // feature quad index

    float4 xi  = ((const float4*)x)[node * 16 + l4];
    float rni  = rn[node];
    float beta = beta_p[0];
    float shift = fabsf(beta);

    int e0 = row_ptr[node];
    int e1 = row_ptr[node + 1];
    int deg = e1 - e0;

    float s = 0.f;
    float4 acc = {0.f, 0.f, 0.f, 0.f};

    for (int base = 0; base < deg; base += 4) {
        int ei = base + g;
        bool valid = ei < deg;
        int e = e0 + (valid ? ei : deg - 1);   // clamp for safe gather
        int c = edge_col[e];
        float4 xc = ((const float4*)x)[c * 16 + l4];
        float rnc = rn[c];

        float d = xc.x * xi.x + xc.y * xi.y + xc.z * xi.z + xc.w * xi.w;
        #pragma unroll
        for (int off = 1; off < 16; off <<= 1)
            d += __shfl_xor(d, off, 64);       // reduce within 16-lane group

        float sim = beta * d * rni * rnc;
        float w = valid ? __expf(sim - shift) : 0.f;
        s += w;
        acc.x += w * xc.x;
        acc.y += w * xc.y;
        acc.z += w * xc.z;
        acc.w += w * xc.w;
    }

    // combine the 4 groups (offsets 16, 32)
    #pragma unroll
    for (int off = 16; off < 64; off <<= 1) {
        s     += __shfl_xor(s,     off, 64);
        acc.x += __shfl_xor(acc.x, off, 64);
        acc.y += __shfl_xor(acc.y, off, 64);
        acc.z += __shfl_xor(acc.z, off, 64);
        acc.w += __shfl_xor(acc.w, off, 64);
    }

    if (g == 0) {
        float inv = (deg > 0 && s > 0.f) ? 1.f / s : 0.f;
        float4 o = {acc.x * inv, acc.y * inv, acc.z * inv, acc.w * inv};
        ((float4*)out)[node * 16 + l4] = o;
    }
}

extern "C" void kernel_launch(void* const* d_in, const int* in_sizes, int n_in,
                              void* d_out, int out_size, void* d_ws, size_t ws_size,
                              hipStream_t stream) {
    const float* x        = (const float*)d_in[0];
    const float* beta     = (const float*)d_in[1];
    const int*   edge_row = (const int*)d_in[2];
    const int*   edge_col = (const int*)d_in[3];
    float* out = (float*)d_out;

    int n_nodes = in_sizes[0] / D_FEAT;
    int n_edges = in_sizes[2];

    // workspace: rn [n_nodes] floats, then row_ptr [n_nodes+1] ints
    float* rn = (float*)d_ws;
    size_t rn_bytes = ((size_t)n_nodes * sizeof(float) + 255) & ~(size_t)255;
    int* row_ptr = (int*)((char*)d_ws + rn_bytes);

    // K1: reciprocal norms — 16 threads per node
    {
        long long threads = (long long)n_nodes * 16;
        int blocks = (int)((threads + 255) / 256);
        agnn_rnorm<<<blocks, 256, 0, stream>>>(x, rn, n_nodes);
    }
    // K2: row_ptr
    {
        int blocks = (n_nodes + 1 + 255) / 256;
        agnn_rowptr<<<blocks, 256, 0, stream>>>(edge_row, row_ptr, n_nodes, n_edges);
    }
    // K3: fused — one wave per node, 4 waves per block
    {
        int blocks = (n_nodes + 3) / 4;
        agnn_fused<<<blocks, 256, 0, stream>>>(x, beta, edge_col, row_ptr, rn,
                                               out, n_nodes);
    }
}

// Round 3
// 150.327 us; speedup vs baseline: 1.9661x; 1.0866x over previous
//
#include <hip/hip_runtime.h>
#include <math.h>

#define D_FEAT 64

// Kernel 1: reciprocal L2 norms. 16 lanes per node, float4 per lane.
__global__ __launch_bounds__(256)
void agnn_rnorm(const float* __restrict__ x, float* __restrict__ rn, int n_nodes) {
    int t = blockIdx.x * blockDim.x + threadIdx.x;
    int node = t >> 4;
    if (node >= n_nodes) return;
    int l4 = t & 15;
    float4 v = ((const float4*)x)[node * 16 + l4];
    float ss = v.x * v.x + v.y * v.y + v.z * v.z + v.w * v.w;
    #pragma unroll
    for (int off = 1; off < 16; off <<= 1)
        ss += __shfl_xor(ss, off, 64);
    if (l4 == 0) rn[node] = ss > 0.f ? rsqrtf(ss) : 0.f;
}

// Kernel 2: CSR row offsets via boundary scatter (edge_row sorted).
// row_ptr[i] = lower_bound(edge_row, i).  Thread e fills row_ptr for all
// rows in (edge_row[e-1], edge_row[e]]; thread 0 fills [0, edge_row[0]];
// the last thread fills the tail up to n_nodes.
__global__ __launch_bounds__(256)
void agnn_rowptr(const int* __restrict__ edge_row, int* __restrict__ row_ptr,
                 int n_nodes, int n_edges) {
    int e = blockIdx.x * blockDim.x + threadIdx.x;
    if (e >= n_edges) return;
    int r1 = edge_row[e];
    int r0 = (e == 0) ? -1 : edge_row[e - 1];
    for (int r = r0 + 1; r <= r1; ++r) row_ptr[r] = e;
    if (e == n_edges - 1) {
        for (int r = r1 + 1; r <= n_nodes; ++r) row_ptr[r] = n_edges;
    }
}

// Kernel 3: fused sim + softmax + SPMM.
// One wave per node; 4 groups of 16 lanes; 2x unrolled: group g handles
// edges (base+g) and (base+4+g) -> 8 gathers in flight per wave.
// Softmax shift is the constant |beta| (|cos|<=1): no rescale chain.
__global__ __launch_bounds__(256)
void agnn_fused(const float* __restrict__ x,
                const float* __restrict__ beta_p,
                const int* __restrict__ edge_col,
                const int* __restrict__ row_ptr,
                const float* __restrict__ rn,
                float* __restrict__ out, int n_nodes) {
    int node = (blockIdx.x * blockDim.x + threadIdx.x) >> 6;
    if (node >= n_nodes) return;
    int lane = threadIdx.x & 63;
    int g  = lane >> 4;    // edge subgroup 0..3
    int l4 = lane & 15;    // feature quad index

    const float4* x4 = (const float4*)x;
    float4 xi  = x4[node * 16 + l4];
    float beta = beta_p[0];
    float brni = beta * rn[node];
    float shift = fabsf(beta);

    int es = row_ptr[node];
    int deg = row_ptr[node + 1] - es;

    float s = 0.f;
    float4 acc = {0.f, 0.f, 0.f, 0.f};

    for (int base = 0; base < deg; base += 8) {
        int ei0 = base + g;
        int ei1 = base + 4 + g;
        bool v0 = ei0 < deg;
        bool v1 = ei1 < deg;
        int ea = es + (v0 ? ei0 : 0);
        int eb = es + (v1 ? ei1 : 0);
        int c0 = edge_col[ea];
        int c1 = edge_col[eb];
        float4 a = x4[c0 * 16 + l4];
        float4 b = x4[c1 * 16 + l4];
        float rn0 = rn[c0];
        float rn1 = rn[c1];

        float d0 = a.x * xi.x + a.y * xi.y + a.z * xi.z + a.w * xi.w;
        float d1 = b.x * xi.x + b.y * xi.y + b.z * xi.z + b.w * xi.w;
        #pragma unroll
        for (int off = 1; off < 16; off <<= 1) {
            d0 += __shfl_xor(d0, off, 64);
            d1 += __shfl_xor(d1, off, 64);
        }

        float w0 = v0 ? __expf(brni * d0 * rn0 - shift) : 0.f;
        float w1 = v1 ? __expf(brni * d1 * rn1 - shift) : 0.f;
        s += w0 + w1;
        acc.x += w0 * a.x + w1 * b.x;
        acc.y += w0 * a.y + w1 * b.y;
        acc.z += w0 * a.z + w1 * b.z;
        acc.w += w0 * a.w + w1 * b.w;
    }

    // combine the 4 groups (offsets 16, 32)
    #pragma unroll
    for (int off = 16; off < 64; off <<= 1) {
        s     += __shfl_xor(s,     off, 64);
        acc.x += __shfl_xor(acc.x, off, 64);
        acc.y += __shfl_xor(acc.y, off, 64);
        acc.z += __shfl_xor(acc.z, off, 64);
        acc.w += __shfl_xor(acc.w, off, 64);
    }

    if (g == 0) {
        float inv = (deg > 0 && s > 0.f) ? 1.f / s : 0.f;
        float4 o = {acc.x * inv, acc.y * inv, acc.z * inv, acc.w * inv};
        ((float4*)out)[node * 16 + l4] = o;
    }
}

extern "C" void kernel_launch(void* const* d_in, const int* in_sizes, int n_in,
                              void* d_out, int out_size, void* d_ws, size_t ws_size,
                              hipStream_t stream) {
    const float* x        = (const float*)d_in[0];
    const float* beta     = (const float*)d_in[1];
    const int*   edge_row = (const int*)d_in[2];
    const int*   edge_col = (const int*)d_in[3];
    float* out = (float*)d_out;

    int n_nodes = in_sizes[0] / D_FEAT;
    int n_edges = in_sizes[2];

    // workspace: rn [n_nodes] floats, then row_ptr [n_nodes+1] ints
    float* rn = (float*)d_ws;
    size_t rn_bytes = ((size_t)n_nodes * sizeof(float) + 255) & ~(size_t)255;
    int* row_ptr = (int*)((char*)d_ws + rn_bytes);

    // K1: reciprocal norms — 16 threads per node
    {
        long long threads = (long long)n_nodes * 16;
        int blocks = (int)((threads + 255) / 256);
        agnn_rnorm<<<blocks, 256, 0, stream>>>(x, rn, n_nodes);
    }
    // K2: row_ptr via boundary scatter — E threads
    {
        int blocks = (n_edges + 255) / 256;
        agnn_rowptr<<<blocks, 256, 0, stream>>>(edge_row, row_ptr, n_nodes, n_edges);
    }
    // K3: fused — one wave per node, 4 waves per block
    {
        int blocks = (n_nodes + 3) / 4;
        agnn_fused<<<blocks, 256, 0, stream>>>(x, beta, edge_col, row_ptr, rn,
                                               out, n_nodes);
    }
}

// Round 4
// 144.504 us; speedup vs baseline: 2.0454x; 1.0403x over previous
//
#include <hip/hip_runtime.h>
#include <math.h>

#define D_FEAT 64
typedef unsigned int u32;

__device__ __forceinline__ unsigned short f2bf_rne(float f) {
    u32 u = __float_as_uint(f);
    u32 r = u + 0x7FFFu + ((u >> 16) & 1u);   // round-to-nearest-even
    return (unsigned short)(r >> 16);
}

// K0: per-node reciprocal L2 norm + bf16 copy of x (gather-compressed).
// 16 lanes per node, float4 per lane.
__global__ __launch_bounds__(256)
void agnn_prep(const float* __restrict__ x, float* __restrict__ rn,
               ushort4* __restrict__ xh, int n_nodes) {
    int t = blockIdx.x * blockDim.x + threadIdx.x;
    int node = t >> 4;
    if (node >= n_nodes) return;
    int l4 = t & 15;
    float4 v = ((const float4*)x)[node * 16 + l4];
    float ss = v.x * v.x + v.y * v.y + v.z * v.z + v.w * v.w;
    #pragma unroll
    for (int off = 1; off < 16; off <<= 1)
        ss += __shfl_xor(ss, off, 64);
    if (l4 == 0) rn[node] = ss > 0.f ? rsqrtf(ss) : 0.f;
    ushort4 h;
    h.x = f2bf_rne(v.x); h.y = f2bf_rne(v.y);
    h.z = f2bf_rne(v.z); h.w = f2bf_rne(v.w);
    xh[node * 16 + l4] = h;
}

// K2: CSR row offsets via boundary scatter (edge_row sorted).
__global__ __launch_bounds__(256)
void agnn_rowptr(const int* __restrict__ edge_row, int* __restrict__ row_ptr,
                 int n_nodes, int n_edges) {
    int e = blockIdx.x * blockDim.x + threadIdx.x;
    if (e >= n_edges) return;
    int r1 = edge_row[e];
    int r0 = (e == 0) ? -1 : edge_row[e - 1];
    for (int r = r0 + 1; r <= r1; ++r) row_ptr[r] = e;
    if (e == n_edges - 1) {
        for (int r = r1 + 1; r <= n_nodes; ++r) row_ptr[r] = n_edges;
    }
}

// K3: fused sim + softmax + SPMM.
// One wave per node; 8 groups of 8 lanes; group g handles edge (base+g).
// Lane l8 holds features [8*l8, 8*l8+8): gathers 8 bf16 = 16 B (uint4),
// so one VMEM instruction covers 8 edges at 128 B/edge.
// Invalid groups skip the gather under exec mask (no padding traffic).
// Softmax shift = |beta| (|cos|<=1): no per-edge max/rescale chain.
__global__ __launch_bounds__(256)
void agnn_fused(const float* __restrict__ x,
                const float* __restrict__ beta_p,
                const int* __restrict__ edge_col,
                const int* __restrict__ row_ptr,
                const float* __restrict__ rn,
                const ushort4* __restrict__ xh,
                float* __restrict__ out, int n_nodes) {
    int node = (blockIdx.x * blockDim.x + threadIdx.x) >> 6;
    if (node >= n_nodes) return;
    int lane = threadIdx.x & 63;
    int g  = lane >> 3;   // edge subgroup 0..7
    int l8 = lane & 7;    // feature octet index

    const float4* x4 = (const float4*)x;
    float4 xiLo = x4[node * 16 + 2 * l8];
    float4 xiHi = x4[node * 16 + 2 * l8 + 1];
    float beta = beta_p[0];
    float brni = beta * rn[node];
    float shift = fabsf(beta);

    int es  = row_ptr[node];
    int deg = row_ptr[node + 1] - es;

    float s = 0.f;
    float4 accLo = {0.f, 0.f, 0.f, 0.f};
    float4 accHi = {0.f, 0.f, 0.f, 0.f};

    const uint4* xh4 = (const uint4*)xh;   // node row = 8 uint4

    for (int base = 0; base < deg; base += 8) {
        int ei = base + g;
        bool valid = ei < deg;
        float4 aLo = {0.f, 0.f, 0.f, 0.f};
        float4 aHi = {0.f, 0.f, 0.f, 0.f};
        float rnc = 0.f;
        if (valid) {
            int c = edge_col[es + ei];
            uint4 u = xh4[(size_t)c * 8 + l8];
            rnc = rn[c];
            aLo.x = __uint_as_float(u.x << 16);
            aLo.y = __uint_as_float(u.x & 0xFFFF0000u);
            aLo.z = __uint_as_float(u.y << 16);
            aLo.w = __uint_as_float(u.y & 0xFFFF0000u);
            aHi.x = __uint_as_float(u.z << 16);
            aHi.y = __uint_as_float(u.z & 0xFFFF0000u);
            aHi.z = __uint_as_float(u.w << 16);
            aHi.w = __uint_as_float(u.w & 0xFFFF0000u);
        }
        float d = aLo.x * xiLo.x + aLo.y * xiLo.y + aLo.z * xiLo.z + aLo.w * xiLo.w
                + aHi.x * xiHi.x + aHi.y * xiHi.y + aHi.z * xiHi.z + aHi.w * xiHi.w;
        #pragma unroll
        for (int off = 1; off < 8; off <<= 1)
            d += __shfl_xor(d, off, 64);     // reduce within 8-lane group
        float w = valid ? __expf(brni * d * rnc - shift) : 0.f;
        s += w;
        accLo.x += w * aLo.x; accLo.y += w * aLo.y;
        accLo.z += w * aLo.z; accLo.w += w * aLo.w;
        accHi.x += w * aHi.x; accHi.y += w * aHi.y;
        accHi.z += w * aHi.z; accHi.w += w * aHi.w;
    }

    // combine the 8 groups (offsets 8, 16, 32)
    #pragma unroll
    for (int off = 8; off < 64; off <<= 1) {
        s       += __shfl_xor(s,       off, 64);
        accLo.x += __shfl_xor(accLo.x, off, 64);
        accLo.y += __shfl_xor(accLo.y, off, 64);
        accLo.z += __shfl_xor(accLo.z, off, 64);
        accLo.w += __shfl_xor(accLo.w, off, 64);
        accHi.x += __shfl_xor(accHi.x, off, 64);
        accHi.y += __shfl_xor(accHi.y, off, 64);
        accHi.z += __shfl_xor(accHi.z, off, 64);
        accHi.w += __shfl_xor(accHi.w, off, 64);
    }

    if (g == 0) {
        float inv = (deg > 0 && s > 0.f) ? 1.f / s : 0.f;
        float4 oLo = {accLo.x * inv, accLo.y * inv, accLo.z * inv, accLo.w * inv};
        float4 oHi = {accHi.x * inv, accHi.y * inv, accHi.z * inv, accHi.w * inv};
        float4* o4 = (float4*)out;
        o4[node * 16 + 2 * l8]     = oLo;
        o4[node * 16 + 2 * l8 + 1] = oHi;
    }
}

extern "C" void kernel_launch(void* const* d_in, const int* in_sizes, int n_in,
                              void* d_out, int out_size, void* d_ws, size_t ws_size,
                              hipStream_t stream) {
    const float* x        = (const float*)d_in[0];
    const float* beta     = (const float*)d_in[1];
    const int*   edge_row = (const int*)d_in[2];
    const int*   edge_col = (const int*)d_in[3];
    float* out = (float*)d_out;

    int n_nodes = in_sizes[0] / D_FEAT;
    int n_edges = in_sizes[2];

    // workspace: rn [n_nodes] f32 | row_ptr [n_nodes+1] i32 | xh [n_nodes*64] bf16
    char* ws = (char*)d_ws;
    float* rn = (float*)ws;
    size_t off0 = ((size_t)n_nodes * sizeof(float) + 255) & ~(size_t)255;
    int* row_ptr = (int*)(ws + off0);
    size_t off1 = off0 + (((size_t)(n_nodes + 1) * sizeof(int) + 255) & ~(size_t)255);
    ushort4* xh = (ushort4*)(ws + off1);

    // K0: rn + bf16 copy — 16 threads per node
    {
        long long threads = (long long)n_nodes * 16;
        int blocks = (int)((threads + 255) / 256);
        agnn_prep<<<blocks, 256, 0, stream>>>(x, rn, xh, n_nodes);
    }
    // K2: row_ptr via boundary scatter
    {
        int blocks = (n_edges + 255) / 256;
        agnn_rowptr<<<blocks, 256, 0, stream>>>(edge_row, row_ptr, n_nodes, n_edges);
    }
    // K3: fused — one wave per node, 4 waves per block
    {
        int blocks = (n_nodes + 3) / 4;
        agnn_fused<<<blocks, 256, 0, stream>>>(x, beta, edge_col, row_ptr, rn,
                                               xh, out, n_nodes);
    }
}

// Round 5
// 137.321 us; speedup vs baseline: 2.1524x; 1.0523x over previous
//
#include <hip/hip_runtime.h>
#include <math.h>

#define D_FEAT 64
typedef _Float16 h2 __attribute__((ext_vector_type(2)));

// dword (2 packed f16) dot f32-accumulate: v_dot2_f32_f16
__device__ __forceinline__ float dot2(unsigned int a, h2 b, float c) {
    h2 av; __builtin_memcpy(&av, &a, 4);
#if __has_builtin(__builtin_amdgcn_fdot2)
    return __builtin_amdgcn_fdot2(av, b, c, false);
#else
    return c + (float)av[0] * (float)b[0] + (float)av[1] * (float)b[1];
#endif
}

__device__ __forceinline__ h2 bits2h2(unsigned int a) {
    h2 av; __builtin_memcpy(&av, &a, 4);
    return av;
}

// K0 (merged): blocks [0, nb_prep): per-node rsqrt-norm + f16 copy of x.
//              blocks [nb_prep, ...): CSR row offsets via boundary scatter.
__global__ __launch_bounds__(256)
void agnn_prep(const float* __restrict__ x, float* __restrict__ rn,
               uint2* __restrict__ xh, const int* __restrict__ edge_row,
               int* __restrict__ row_ptr, int n_nodes, int n_edges, int nb_prep) {
    if ((int)blockIdx.x < nb_prep) {
        int t = blockIdx.x * blockDim.x + threadIdx.x;
        int node = t >> 4;
        if (node >= n_nodes) return;
        int l4 = t & 15;
        float4 v = ((const float4*)x)[node * 16 + l4];
        float ss = v.x * v.x + v.y * v.y + v.z * v.z + v.w * v.w;
        #pragma unroll
        for (int off = 1; off < 16; off <<= 1)
            ss += __shfl_xor(ss, off, 64);
        if (l4 == 0) rn[node] = ss > 0.f ? rsqrtf(ss) : 0.f;
        h2 h0 = {( _Float16)v.x, (_Float16)v.y};
        h2 h1 = {( _Float16)v.z, (_Float16)v.w};
        uint2 u;
        __builtin_memcpy(&u.x, &h0, 4);
        __builtin_memcpy(&u.y, &h1, 4);
        xh[node * 16 + l4] = u;
    } else {
        int e = (blockIdx.x - nb_prep) * blockDim.x + threadIdx.x;
        if (e >= n_edges) return;
        int r1 = edge_row[e];
        int r0 = (e == 0) ? -1 : edge_row[e - 1];
        for (int r = r0 + 1; r <= r1; ++r) row_ptr[r] = e;
        if (e == n_edges - 1) {
            for (int r = r1 + 1; r <= n_nodes; ++r) row_ptr[r] = n_edges;
        }
    }
}

// K1: fused sim + softmax + SPMM.
// One wave per node; 8 groups of 8 lanes; 2x unrolled: group g handles
// edges (base+g) and (base+8+g).  Lane l8 holds features [8*l8, 8*l8+8)
// as 4 packed-f16 dwords (one uint4 gather = 128 B/edge).
// Dot: v_dot2_f32_f16 x4.  Accumulate: v_pk_fma_f16 x4.
// Softmax shift = |beta| (|cos|<=1): no per-edge max/rescale chain.
__global__ __launch_bounds__(256)
void agnn_fused(const float* __restrict__ x,
                const float* __restrict__ beta_p,
                const int* __restrict__ edge_col,
                const int* __restrict__ row_ptr,
                const float* __restrict__ rn,
                const uint4* __restrict__ xh4,
                float* __restrict__ out, int n_nodes) {
    int node = (blockIdx.x * blockDim.x + threadIdx.x) >> 6;
    if (node >= n_nodes) return;
    int lane = threadIdx.x & 63;
    int g  = lane >> 3;   // edge subgroup 0..7
    int l8 = lane & 7;    // feature octet index

    const float4* x4 = (const float4*)x;
    float4 xiLo = x4[node * 16 + 2 * l8];
    float4 xiHi = x4[node * 16 + 2 * l8 + 1];
    h2 xi0 = {( _Float16)xiLo.x, (_Float16)xiLo.y};
    h2 xi1 = {( _Float16)xiLo.z, (_Float16)xiLo.w};
    h2 xi2 = {( _Float16)xiHi.x, (_Float16)xiHi.y};
    h2 xi3 = {( _Float16)xiHi.z, (_Float16)xiHi.w};

    float beta = beta_p[0];
    float brni = beta * rn[node];
    float shift = fabsf(beta);

    int es  = row_ptr[node];
    int deg = row_ptr[node + 1] - es;

    float s = 0.f;
    h2 acc0 = {0, 0}, acc1 = {0, 0}, acc2 = {0, 0}, acc3 = {0, 0};

    for (int base = 0; base < deg; base += 16) {
        int ei0 = base + g;
        int ei1 = base + 8 + g;
        bool v0 = ei0 < deg;
        bool v1 = ei1 < deg;
        uint4 u0 = {0, 0, 0, 0};
        uint4 u1 = {0, 0, 0, 0};
        float rn0 = 0.f, rn1 = 0.f;
        if (v0) {
            int c = edge_col[es + ei0];
            u0 = xh4[(size_t)c * 8 + l8];
            rn0 = rn[c];
        }
        if (v1) {
            int c = edge_col[es + ei1];
            u1 = xh4[(size_t)c * 8 + l8];
            rn1 = rn[c];
        }

        float d0 = dot2(u0.x, xi0, 0.f);
        d0 = dot2(u0.y, xi1, d0);
        d0 = dot2(u0.z, xi2, d0);
        d0 = dot2(u0.w, xi3, d0);
        float d1 = dot2(u1.x, xi0, 0.f);
        d1 = dot2(u1.y, xi1, d1);
        d1 = dot2(u1.z, xi2, d1);
        d1 = dot2(u1.w, xi3, d1);
        #pragma unroll
        for (int off = 1; off < 8; off <<= 1) {
            d0 += __shfl_xor(d0, off, 64);
            d1 += __shfl_xor(d1, off, 64);
        }

        float w0 = v0 ? __expf(brni * d0 * rn0 - shift) : 0.f;
        float w1 = v1 ? __expf(brni * d1 * rn1 - shift) : 0.f;
        s += w0 + w1;

        h2 w02 = {( _Float16)w0, (_Float16)w0};
        h2 w12 = {( _Float16)w1, (_Float16)w1};
        acc0 = bits2h2(u0.x) * w02 + acc0;
        acc1 = bits2h2(u0.y) * w02 + acc1;
        acc2 = bits2h2(u0.z) * w02 + acc2;
        acc3 = bits2h2(u0.w) * w02 + acc3;
        acc0 = bits2h2(u1.x) * w12 + acc0;
        acc1 = bits2h2(u1.y) * w12 + acc1;
        acc2 = bits2h2(u1.z) * w12 + acc2;
        acc3 = bits2h2(u1.w) * w12 + acc3;
    }

    // convert accumulators to f32 and combine the 8 groups (offsets 8,16,32)
    float f0 = (float)acc0[0], f1 = (float)acc0[1];
    float f2 = (float)acc1[0], f3 = (float)acc1[1];
    float f4 = (float)acc2[0], f5 = (float)acc2[1];
    float f6 = (float)acc3[0], f7 = (float)acc3[1];
    #pragma unroll
    for (int off = 8; off < 64; off <<= 1) {
        s  += __shfl_xor(s,  off, 64);
        f0 += __shfl_xor(f0, off, 64);
        f1 += __shfl_xor(f1, off, 64);
        f2 += __shfl_xor(f2, off, 64);
        f3 += __shfl_xor(f3, off, 64);
        f4 += __shfl_xor(f4, off, 64);
        f5 += __shfl_xor(f5, off, 64);
        f6 += __shfl_xor(f6, off, 64);
        f7 += __shfl_xor(f7, off, 64);
    }

    if (g == 0) {
        float inv = (deg > 0 && s > 0.f) ? 1.f / s : 0.f;
        float4 oLo = {f0 * inv, f1 * inv, f2 * inv, f3 * inv};
        float4 oHi = {f4 * inv, f5 * inv, f6 * inv, f7 * inv};
        float4* o4 = (float4*)out;
        o4[node * 16 + 2 * l8]     = oLo;
        o4[node * 16 + 2 * l8 + 1] = oHi;
    }
}

extern "C" void kernel_launch(void* const* d_in, const int* in_sizes, int n_in,
                              void* d_out, int out_size, void* d_ws, size_t ws_size,
                              hipStream_t stream) {
    const float* x        = (const float*)d_in[0];
    const float* beta     = (const float*)d_in[1];
    const int*   edge_row = (const int*)d_in[2];
    const int*   edge_col = (const int*)d_in[3];
    float* out = (float*)d_out;

    int n_nodes = in_sizes[0] / D_FEAT;
    int n_edges = in_sizes[2];

    // workspace: rn [n_nodes] f32 | row_ptr [n_nodes+1] i32 | xh [n_nodes*64] f16
    char* ws = (char*)d_ws;
    float* rn = (float*)ws;
    size_t off0 = ((size_t)n_nodes * sizeof(float) + 255) & ~(size_t)255;
    int* row_ptr = (int*)(ws + off0);
    size_t off1 = off0 + (((size_t)(n_nodes + 1) * sizeof(int) + 255) & ~(size_t)255);
    uint2* xh = (uint2*)(ws + off1);

    // K0: merged prep (norms + f16 copy) and row_ptr scatter
    {
        int nb_prep = (n_nodes * 16 + 255) / 256;
        int nb_rp   = (n_edges + 255) / 256;
        agnn_prep<<<nb_prep + nb_rp, 256, 0, stream>>>(
            x, rn, xh, edge_row, row_ptr, n_nodes, n_edges, nb_prep);
    }
    // K1: fused — one wave per node, 4 waves per block
    {
        int blocks = (n_nodes + 3) / 4;
        agnn_fused<<<blocks, 256, 0, stream>>>(x, beta, edge_col, row_ptr, rn,
                                               (const uint4*)xh, out, n_nodes);
    }
}

// Round 6
// 130.721 us; speedup vs baseline: 2.2610x; 1.0505x over previous
//
#include <hip/hip_runtime.h>
#include <math.h>

#define D_FEAT 64
#define S_GET(v, i) ((v)[i])
typedef _Float16 v8h __attribute__((ext_vector_type(8)));
typedef float v4f __attribute__((ext_vector_type(4)));
typedef _Float16 h2 __attribute__((ext_vector_type(2)));

__device__ __forceinline__ v8h u2h8(uint4 u) { v8h v; __builtin_memcpy(&v, &u, 16); return v; }

// ---- K0 (merged): blocks [0,nb_prep): per-node rsqrt-norm + f16 copy of x.
//      blocks [nb_prep,..): CSR row offsets via boundary scatter (rows sorted).
__global__ __launch_bounds__(256)
void agnn_prep(const float* __restrict__ x, float* __restrict__ rn,
               uint2* __restrict__ xh, const int* __restrict__ edge_row,
               int* __restrict__ row_ptr, int n_nodes, int n_edges, int nb_prep) {
    if ((int)blockIdx.x < nb_prep) {
        int t = blockIdx.x * blockDim.x + threadIdx.x;
        int node = t >> 4;
        if (node >= n_nodes) return;
        int l4 = t & 15;
        float4 v = ((const float4*)x)[node * 16 + l4];
        float ss = v.x*v.x + v.y*v.y + v.z*v.z + v.w*v.w;
        #pragma unroll
        for (int off = 1; off < 16; off <<= 1) ss += __shfl_xor(ss, off, 64);
        if (l4 == 0) rn[node] = ss > 0.f ? rsqrtf(ss) : 0.f;
        h2 h0 = {(_Float16)v.x, (_Float16)v.y};
        h2 h1 = {(_Float16)v.z, (_Float16)v.w};
        uint2 u;
        __builtin_memcpy(&u.x, &h0, 4);
        __builtin_memcpy(&u.y, &h1, 4);
        xh[node * 16 + l4] = u;
    } else {
        int e = (blockIdx.x - nb_prep) * blockDim.x + threadIdx.x;
        if (e >= n_edges) return;
        int r1 = edge_row[e];
        int r0 = (e == 0) ? -1 : edge_row[e - 1];
        for (int r = r0 + 1; r <= r1; ++r) row_ptr[r] = e;
        if (e == n_edges - 1)
            for (int r = r1 + 1; r <= n_nodes; ++r) row_ptr[r] = n_edges;
    }
}

// ---- K1: block-sparse flash-style fused kernel ----
// One WAVE per tile of 16 consecutive nodes (CSR edges contiguous per tile).
// Per 32-edge superchunk: S = Q.Xc^T (4x mfma 16x16x32 f16), block-sparse
// mask w = (edge_row==row)?exp(beta*rni*rnc*S - |beta|):0, then O += P.Xc
// (4x mfma; P relaid C->A through wave-private LDS; Xc staged feat-pair-major
// for the V operand: ds_read_b128 + v_perm half-select).  No barriers.
// Layouts per guide Sec.3: C/D col=lane&15,row=quad*4+reg; A m=lane&15,k=quad*8+j.
#define XCP_PITCH 144
#define P_PITCH    80
#define WAVE_LDS  (32 * XCP_PITCH + 16 * P_PITCH)

__global__ __launch_bounds__(256)
void agnn_fused(const float* __restrict__ beta_p,
                const int* __restrict__ edge_col,
                const int* __restrict__ edge_row,
                const int* __restrict__ row_ptr,
                const float* __restrict__ rn,
                const uint4* __restrict__ xh4,
                float* __restrict__ out, int n_nodes) {
    __shared__ char lds_raw[4 * WAVE_LDS];
    int wid  = threadIdx.x >> 6;
    int lane = threadIdx.x & 63;
    int q    = lane >> 4;
    int lo4  = lane & 15;
    char* XCP = lds_raw + wid * WAVE_LDS;
    char* PL  = XCP + 32 * XCP_PITCH;

    int tile = blockIdx.x * 4 + wid;
    int t0 = tile * 16;
    if (t0 >= n_nodes) return;

    int qnode = t0 + lo4; if (qnode >= n_nodes) qnode = n_nodes - 1;
    v8h a0 = u2h8(xh4[(size_t)qnode * 8 + q]);
    v8h a1 = u2h8(xh4[(size_t)qnode * 8 + 4 + q]);

    float beta  = beta_p[0];
    float shift = fabsf(beta);
    float4 rq = *(const float4*)(rn + t0 + q * 4);
    float brn0 = beta * rq.x, brn1 = beta * rq.y, brn2 = beta * rq.z, brn3 = beta * rq.w;

    int es   = row_ptr[t0];
    int tend = t0 + 16; if (tend > n_nodes) tend = n_nodes;
    int L    = row_ptr[tend] - es;

    v4f o0 = {0,0,0,0}, o1 = {0,0,0,0}, o2 = {0,0,0,0}, o3 = {0,0,0,0};
    float l0 = 0.f, l1 = 0.f, l2 = 0.f, l3 = 0.f;
    unsigned int selp = (lo4 & 1) ? 0x07060302u : 0x05040100u;
    int rbase = t0 + q * 4;

    for (int base = 0; base < L; base += 32) {
        int idx0 = base + lo4;
        bool cv0 = idx0 < L;
        int e0 = es + (cv0 ? idx0 : 0);
        int c0 = edge_col[e0];
        int rr0 = edge_row[e0];
        float rnc0 = rn[c0];
        uint4 u00 = xh4[(size_t)c0 * 8 + q];
        uint4 u01 = xh4[(size_t)c0 * 8 + 4 + q];
        int idx1 = base + 16 + lo4;
        bool cv1 = idx1 < L;
        int e1 = es + (cv1 ? idx1 : 0);
        int c1 = edge_col[e1];
        int rr1 = edge_row[e1];
        float rnc1 = rn[c1];
        uint4 u10 = xh4[(size_t)c1 * 8 + q];
        uint4 u11 = xh4[(size_t)c1 * 8 + 4 + q];

        v4f z0 = {0,0,0,0};
        z0 = __builtin_amdgcn_mfma_f32_16x16x32_f16(a0, u2h8(u00), z0, 0, 0, 0);
        z0 = __builtin_amdgcn_mfma_f32_16x16x32_f16(a1, u2h8(u01), z0, 0, 0, 0);
        v4f z1 = {0,0,0,0};
        z1 = __builtin_amdgcn_mfma_f32_16x16x32_f16(a0, u2h8(u10), z1, 0, 0, 0);
        z1 = __builtin_amdgcn_mfma_f32_16x16x32_f16(a1, u2h8(u11), z1, 0, 0, 0);

        {
            unsigned int colA = lo4 * 4, colB = (16 + lo4) * 4;
            char* pA = XCP + (4 * q) * XCP_PITCH;
            char* pB = XCP + (16 + 4 * q) * XCP_PITCH;
            *(unsigned int*)(pA + 0 * XCP_PITCH + colA) = u00.x;
            *(unsigned int*)(pA + 1 * XCP_PITCH + colA) = u00.y;
            *(unsigned int*)(pA + 2 * XCP_PITCH + colA) = u00.z;
            *(unsigned int*)(pA + 3 * XCP_PITCH + colA) = u00.w;
            *(unsigned int*)(pB + 0 * XCP_PITCH + colA) = u01.x;
            *(unsigned int*)(pB + 1 * XCP_PITCH + colA) = u01.y;
            *(unsigned int*)(pB + 2 * XCP_PITCH + colA) = u01.z;
            *(unsigned int*)(pB + 3 * XCP_PITCH + colA) = u01.w;
            *(unsigned int*)(pA + 0 * XCP_PITCH + colB) = u10.x;
            *(unsigned int*)(pA + 1 * XCP_PITCH + colB) = u10.y;
            *(unsigned int*)(pA + 2 * XCP_PITCH + colB) = u10.z;
            *(unsigned int*)(pA + 3 * XCP_PITCH + colB) = u10.w;
            *(unsigned int*)(pB + 0 * XCP_PITCH + colB) = u11.x;
            *(unsigned int*)(pB + 1 * XCP_PITCH + colB) = u11.y;
            *(unsigned int*)(pB + 2 * XCP_PITCH + colB) = u11.z;
            *(unsigned int*)(pB + 3 * XCP_PITCH + colB) = u11.w;
        }

        float w00 = (cv0 && rr0 == rbase + 0) ? __expf(brn0 * rnc0 * z0[0] - shift) : 0.f;
        float w01 = (cv0 && rr0 == rbase + 1) ? __expf(brn1 * rnc0 * z0[1] - shift) : 0.f;
        float w02 = (cv0 && rr0 == rbase + 2) ? __expf(brn2 * rnc0 * z0[2] - shift) : 0.f;
        float w03 = (cv0 && rr0 == rbase + 3) ? __expf(brn3 * rnc0 * z0[3] - shift) : 0.f;
        float w10 = (cv1 && rr1 == rbase + 0) ? __expf(brn0 * rnc1 * z1[0] - shift) : 0.f;
        float w11 = (cv1 && rr1 == rbase + 1) ? __expf(brn1 * rnc1 * z1[1] - shift) : 0.f;
        float w12 = (cv1 && rr1 == rbase + 2) ? __expf(brn2 * rnc1 * z1[2] - shift) : 0.f;
        float w13 = (cv1 && rr1 == rbase + 3) ? __expf(brn3 * rnc1 * z1[3] - shift) : 0.f;
        l0 += w00 + w10; l1 += w01 + w11; l2 += w02 + w12; l3 += w03 + w13;

        {
            unsigned int cA = lo4 * 2, cB = (16 + lo4) * 2;
            char* pm = PL + (q * 4) * P_PITCH;
            *(_Float16*)(pm + 0 * P_PITCH + cA) = (_Float16)w00;
            *(_Float16*)(pm + 1 * P_PITCH + cA) = (_Float16)w01;
            *(_Float16*)(pm + 2 * P_PITCH + cA) = (_Float16)w02;
            *(_Float16*)(pm + 3 * P_PITCH + cA) = (_Float16)w03;
            *(_Float16*)(pm + 0 * P_PITCH + cB) = (_Float16)w10;
            *(_Float16*)(pm + 1 * P_PITCH + cB) = (_Float16)w11;
            *(_Float16*)(pm + 2 * P_PITCH + cB) = (_Float16)w12;
            *(_Float16*)(pm + 3 * P_PITCH + cB) = (_Float16)w13;
        }

        v8h pah = u2h8(*(const uint4*)(PL + lo4 * P_PITCH + q * 16));
        {
            const char* rp = XCP + (0 + (lo4 >> 1)) * XCP_PITCH + q * 32;
            uint4 da = *(const uint4*)rp;
            uint4 db = *(const uint4*)(rp + 16);
            uint4 bb = { __builtin_amdgcn_perm(da.y, da.x, selp),
                         __builtin_amdgcn_perm(da.w, da.z, selp),
                         __builtin_amdgcn_perm(db.y, db.x, selp),
                         __builtin_amdgcn_perm(db.w, db.z, selp) };
            o0 = __builtin_amdgcn_mfma_f32_16x16x32_f16(pah, u2h8(bb), o0, 0, 0, 0);
        }
        {
            const char* rp = XCP + (8 + (lo4 >> 1)) * XCP_PITCH + q * 32;
            uint4 da = *(const uint4*)rp;
            uint4 db = *(const uint4*)(rp + 16);
            uint4 bb = { __builtin_amdgcn_perm(da.y, da.x, selp),
                         __builtin_amdgcn_perm(da.w, da.z, selp),
                         __builtin_amdgcn_perm(db.y, db.x, selp),
                         __builtin_amdgcn_perm(db.w, db.z, selp) };
            o1 = __builtin_amdgcn_mfma_f32_16x16x32_f16(pah, u2h8(bb), o1, 0, 0, 0);
        }
        {
            const char* rp = XCP + (16 + (lo4 >> 1)) * XCP_PITCH + q * 32;
            uint4 da = *(const uint4*)rp;
            uint4 db = *(const uint4*)(rp + 16);
            uint4 bb = { __builtin_amdgcn_perm(da.y, da.x, selp),
                         __builtin_amdgcn_perm(da.w, da.z, selp),
                         __builtin_amdgcn_perm(db.y, db.x, selp),
                         __builtin_amdgcn_perm(db.w, db.z, selp) };
            o2 = __builtin_amdgcn_mfma_f32_16x16x32_f16(pah, u2h8(bb), o2, 0, 0, 0);
        }
        {
            const char* rp = XCP + (24 + (lo4 >> 1)) * XCP_PITCH + q * 32;
            uint4 da = *(const uint4*)rp;
            uint4 db = *(const uint4*)(rp + 16);
            uint4 bb = { __builtin_amdgcn_perm(da.y, da.x, selp),
                         __builtin_amdgcn_perm(da.w, da.z, selp),
                         __builtin_amdgcn_perm(db.y, db.x, selp),
                         __builtin_amdgcn_perm(db.w, db.z, selp) };
            o3 = __builtin_amdgcn_mfma_f32_16x16x32_f16(pah, u2h8(bb), o3, 0, 0, 0);
        }
    }

    #pragma unroll
    for (int off = 1; off < 16; off <<= 1) {
        l0 += __shfl_xor(l0, off, 64);
        l1 += __shfl_xor(l1, off, 64);
        l2 += __shfl_xor(l2, off, 64);
        l3 += __shfl_xor(l3, off, 64);
    }
    float i0 = l0 > 0.f ? 1.f / l0 : 0.f;
    float i1 = l1 > 0.f ? 1.f / l1 : 0.f;
    float i2 = l2 > 0.f ? 1.f / l2 : 0.f;
    float i3 = l3 > 0.f ? 1.f / l3 : 0.f;

    int m0 = rbase;
    if (m0 + 0 < n_nodes) { float* p = out + (size_t)(m0 + 0) * 64 + lo4;
        p[0] = o0[0]*i0; p[16] = o1[0]*i0; p[32] = o2[0]*i0; p[48] = o3[0]*i0; }
    if (m0 + 1 < n_nodes) { float* p = out + (size_t)(m0 + 1) * 64 + lo4;
        p[0] = o0[1]*i1; p[16] = o1[1]*i1; p[32] = o2[1]*i1; p[48] = o3[1]*i1; }
    if (m0 + 2 < n_nodes) { float* p = out + (size_t)(m0 + 2) * 64 + lo4;
        p[0] = o0[2]*i2; p[16] = o1[2]*i2; p[32] = o2[2]*i2; p[48] = o3[2]*i2; }
    if (m0 + 3 < n_nodes) { float* p = out + (size_t)(m0 + 3) * 64 + lo4;
        p[0] = o0[3]*i3; p[16] = o1[3]*i3; p[32] = o2[3]*i3; p[48] = o3[3]*i3; }
}

extern "C" void kernel_launch(void* const* d_in, const int* in_sizes, int n_in,
                              void* d_out, int out_size, void* d_ws, size_t ws_size,
                              hipStream_t stream) {
    const float* x        = (const float*)d_in[0];
    const float* beta     = (const float*)d_in[1];
    const int*   edge_row = (const int*)d_in[2];
    const int*   edge_col = (const int*)d_in[3];
    float* out = (float*)d_out;

    int n_nodes = in_sizes[0] / D_FEAT;
    int n_edges = in_sizes[2];

    char* ws = (char*)d_ws;
    float* rn = (float*)ws;
    size_t off0 = ((size_t)n_nodes * sizeof(float) + 255) & ~(size_t)255;
    int* row_ptr = (int*)(ws + off0);
    size_t off1 = off0 + (((size_t)(n_nodes + 1) * sizeof(int) + 255) & ~(size_t)255);
    uint2* xh = (uint2*)(ws + off1);

    {
        int nb_prep = (n_nodes * 16 + 255) / 256;
        int nb_rp   = (n_edges + 255) / 256;
        agnn_prep<<<nb_prep + nb_rp, 256, 0, stream>>>(
            x, rn, xh, edge_row, row_ptr, n_nodes, n_edges, nb_prep);
    }
    {
        int tiles  = (n_nodes + 15) / 16;
        int blocks = (tiles + 3) / 4;
        agnn_fused<<<blocks, 256, 0, stream>>>(beta, edge_col, edge_row, row_ptr,
                                               rn, (const uint4*)xh, out, n_nodes);
    }
}